// Round 14
// baseline (218.310 us; speedup 1.0000x reference)
//
#include <hip/hip_runtime.h>
#include <hip/hip_bf16.h>
#include <math.h>

// Problem constants (fixed shapes)
#define BATCH   2
#define TSEQ    2048
#define DEMBED  1024
#define NHEAD   16
#define DHEAD   64
#define NGROUP  4
#define ROPEN   32
#define FQKV    1536          // (16 + 2*4) * 64
#define MROWS   (BATCH*TSEQ)  // 4096

typedef __attribute__((ext_vector_type(8))) short short8;   // 8 bf16 = 4 VGPR
typedef __attribute__((ext_vector_type(4))) float floatx4;  // MFMA C/D

// ---------------------------------------------------------------------------
// split helpers: f = hi + lo, hi = truncate-to-bf16(f), lo = bf16(f - hi).
// ---------------------------------------------------------------------------
__device__ __forceinline__ void split_pack8(const float* f, uint4& h4, uint4& l4) {
    uint u[8], lu[8];
    #pragma unroll
    for (int j = 0; j < 8; ++j) {
        u[j] = __float_as_uint(f[j]);
        float lf = f[j] - __uint_as_float(u[j] & 0xffff0000u);
        lu[j] = __float_as_uint(lf);
    }
    h4.x = __builtin_amdgcn_perm(u[1], u[0], 0x07060302u);
    h4.y = __builtin_amdgcn_perm(u[3], u[2], 0x07060302u);
    h4.z = __builtin_amdgcn_perm(u[5], u[4], 0x07060302u);
    h4.w = __builtin_amdgcn_perm(u[7], u[6], 0x07060302u);
    l4.x = __builtin_amdgcn_perm(lu[1], lu[0], 0x07060302u);
    l4.y = __builtin_amdgcn_perm(lu[3], lu[2], 0x07060302u);
    l4.z = __builtin_amdgcn_perm(lu[5], lu[4], 0x07060302u);
    l4.w = __builtin_amdgcn_perm(lu[7], lu[6], 0x07060302u);
}

// round-to-nearest bf16 pack of 8 floats -> hi-only uint4 (unbiased)
__device__ __forceinline__ void rtn_pack8(const float* f, uint4& h4) {
    uint t[8];
    #pragma unroll
    for (int j = 0; j < 8; ++j)
        t[j] = __float_as_uint(f[j]) + 0x8000u;
    h4.x = __builtin_amdgcn_perm(t[1], t[0], 0x07060302u);
    h4.y = __builtin_amdgcn_perm(t[3], t[2], 0x07060302u);
    h4.z = __builtin_amdgcn_perm(t[5], t[4], 0x07060302u);
    h4.w = __builtin_amdgcn_perm(t[7], t[6], 0x07060302u);
}

// pack two floats -> one u32 of two RTN bf16 (lo = f0, hi = f1)
__device__ __forceinline__ uint pk_bf16x2(float f0, float f1) {
    uint u0 = __float_as_uint(f0) + 0x8000u;
    uint u1 = __float_as_uint(f1) + 0x8000u;
    return __builtin_amdgcn_perm(u1, u0, 0x07060302u);
}

// native 2^x (single VOP1; log2 scaling folded into operands upstream)
__device__ __forceinline__ float fast_exp2(float x) {
    float r;
    asm("v_exp_f32 %0, %1" : "=v"(r) : "v"(x));
    return r;
}

// async 16B/lane global->LDS copy; lds must be wave-uniform (HW adds lane*16)
// INVARIANT (session-verified): LDS destination must stay < 64 KiB.
__device__ __forceinline__ void lds_async16(void* lds, const void* gp) {
    __builtin_amdgcn_global_load_lds(
        (const __attribute__((address_space(1))) unsigned int*)gp,
        (__attribute__((address_space(3))) unsigned int*)lds,
        16, 0, 0);
}

// ===========================================================================
// MFMA-GEMM images, format v2 (BK=32 native):
// per (tile128, kb32): contiguous 16 KB region = [hi: 128 rows x 64 B |
// lo: 128 rows x 64 B].  Region index = tile*32 + kb.  Row r holds the
// 32 k-values as 4 chunks of 16 B; logical chunk q stored at slot
// q ^ p(r), p(r) = (r>>1)&3.  Wave b128 read: conflict-free (8 lanes per
// 16-B bank group).  Enables linear 4-KB global_load_lds double-buffering
// below the 64-KiB async-dest envelope.
// ===========================================================================

// ---- x converter body: [4096][1024] f32 row-major -> A-image v2 ----
__device__ __forceinline__ void conv_xy_body(const float* __restrict__ in,
                                             char* __restrict__ img,
                                             int bid, int tid) {
    const int c   = bid & 15;        // 64-k block -> kb = 2c + half
    const int mt  = bid >> 4;
    const int r    = tid >> 1;
    const int half = tid & 1;

    const float* src = in + (size_t)(mt*128 + r)*1024 + c*64 + half*32;
    float f[32];
    #pragma unroll
    for (int u = 0; u < 8; ++u)
        *(float4*)(f + 4*u) = *(const float4*)(src + 4*u);

    char* reg = img + (size_t)(mt*32 + c*2 + half) * 16384;
    const int pr = (r >> 1) & 3;
    #pragma unroll
    for (int cc = 0; cc < 4; ++cc) {
        uint4 h4, l4;
        split_pack8(f + cc*8, h4, l4);
        int slot = cc ^ pr;
        *(uint4*)(reg + r*64 + slot*16)        = h4;
        *(uint4*)(reg + 8192 + r*64 + slot*16) = l4;
    }
}

// ---- weight converter body (transpose): W [1024][N] f32 -> B^T image v2 ----
__device__ __forceinline__ void conv_w_body(const float* __restrict__ W,
                                            int N, char* __restrict__ img,
                                            int c, int nt, int tid,
                                            float (*Lf)[132]) {
    {
        const int kk = tid >> 2;
        const int nc = (tid & 3) * 32;
        const float* src = W + (size_t)(c*64 + kk)*N + nt*128 + nc;
        #pragma unroll
        for (int u = 0; u < 8; ++u)
            *(float4*)(&Lf[kk][nc + 4*u]) = *(const float4*)(src + 4*u);
    }
    __syncthreads();

    char* tbase = img + (size_t)(nt*32 + c*2) * 16384;   // kb even; odd at +16K
    #pragma unroll
    for (int rep = 0; rep < 4; ++rep) {
        int idx = rep*256 + tid;
        int n = idx & 127;
        int j = idx >> 7;                 // logical 8-k chunk of the 64-k block
        float v[8];
        #pragma unroll
        for (int i = 0; i < 8; ++i) v[i] = Lf[j*8 + i][n];
        uint4 h4, l4;
        split_pack8(v, h4, l4);
        char* reg = tbase + (j >> 2)*16384;
        int slot = (j & 3) ^ ((n >> 1) & 3);
        *(uint4*)(reg + n*64 + slot*16)        = h4;
        *(uint4*)(reg + 8192 + n*64 + slot*16) = l4;
    }
}

// ---- merged converter: one launch covers x, Wqkv, Wout conversion ----
__global__ __launch_bounds__(256) void conv_all(const float* __restrict__ x,
                                                const float* __restrict__ Wqkv,
                                                const float* __restrict__ Wout,
                                                char* __restrict__ Ximg,
                                                char* __restrict__ Bq,
                                                char* __restrict__ Bo) {
    __shared__ float Lf[64][132];
    const int bid = blockIdx.x;
    const int tid = threadIdx.x;
    if (bid < 512) {
        conv_xy_body(x, Ximg, bid, tid);
    } else if (bid < 704) {
        const int idx = bid - 512;
        conv_w_body(Wqkv, FQKV, Bq, idx & 15, idx >> 4, tid, Lf);
    } else {
        const int idx = bid - 704;
        conv_w_body(Wout, DEMBED, Bo, idx & 15, idx >> 4, tid, Lf);
    }
}

// ---------------------------------------------------------------------------
// GEMM core "64": 64M x 128N tile, K-step 32, TRUE double buffer (the
// round-13-verified gemm_out core, shared by both GEMMs).  Per step: 6
// linear 4-KB global_load_lds calls into one of two 24-KB buffers; ONE
// barrier per step; prefetch c+1 after the barrier publishing c.
// Buffer: [A-hi 4K][A-lo 4K][B-hi 8K][B-lo 8K]; dbuf 48 KB, dests < 64 KiB.
// amt = 64-row tile index (A half-region = (amt&1)*4096 within 128-row reg).
// ---------------------------------------------------------------------------
__device__ __forceinline__ void gemm_core64(const char* __restrict__ Aimg,
                                            const char* __restrict__ Bimg,
                                            char* smem, int amt, int nt,
                                            int tid, floatx4 (*acc)[4]) {
    const int wv = tid >> 6;
    const int wm = wv & 1, wn = wv >> 1;
    const int lane = tid & 63;
    const int qd = lane >> 4, cl = lane & 15;
    const int wslot = (tid & 192) * 16;
    const int slotx = (cl >> 1) & 3;
    const int ahalf = (amt & 1) * 4096;

    #pragma unroll
    for (int tm = 0; tm < 2; ++tm)
        #pragma unroll
        for (int tn = 0; tn < 4; ++tn)
            acc[tm][tn] = (floatx4){0.f, 0.f, 0.f, 0.f};

    // prologue: stage step 0 into buf 0
    {
        const char* gA = Aimg + (size_t)((amt >> 1)*32)*16384 + (size_t)tid*16;
        const char* gB = Bimg + (size_t)(nt*32)*16384 + (size_t)tid*16;
        lds_async16(smem + wslot,        gA + ahalf);
        lds_async16(smem + 4096 + wslot, gA + 8192 + ahalf);
        #pragma unroll
        for (int j = 0; j < 4; ++j)
            lds_async16(smem + 8192 + j*4096 + wslot, gB + j*4096);
    }

    for (int c = 0; c < 32; ++c) {
        __syncthreads();                    // publishes buf[c&1]; prev reads done
        const int buf = c & 1;
        if (c + 1 < 32) {
            const char* gA = Aimg + (size_t)((amt >> 1)*32 + c+1)*16384 + (size_t)tid*16;
            const char* gB = Bimg + (size_t)(nt*32 + c+1)*16384 + (size_t)tid*16;
            char* dst = smem + (1 - buf)*24576;
            lds_async16(dst + wslot,        gA + ahalf);
            lds_async16(dst + 4096 + wslot, gA + 8192 + ahalf);
            #pragma unroll
            for (int j = 0; j < 4; ++j)
                lds_async16(dst + 8192 + j*4096 + wslot, gB + j*4096);
        }
        const char* S = smem + buf*24576;

        short8 ah[2], al[2], bh[4], bl[4];
        #pragma unroll
        for (int tt = 0; tt < 2; ++tt) {
            const int ra = (wm*32 + 16*tt + cl)*64 + ((qd ^ slotx)*16);
            ah[tt] = *(const short8*)(S + ra);
            al[tt] = *(const short8*)(S + 4096 + ra);
        }
        #pragma unroll
        for (int tt = 0; tt < 4; ++tt) {
            const int rb = (wn*64 + 16*tt + cl)*64 + ((qd ^ slotx)*16);
            bh[tt] = *(const short8*)(S + 8192 + rb);
            bl[tt] = *(const short8*)(S + 16384 + rb);
        }
        #pragma unroll
        for (int tm = 0; tm < 2; ++tm)
            #pragma unroll
            for (int tn = 0; tn < 4; ++tn) {
                acc[tm][tn] = __builtin_amdgcn_mfma_f32_16x16x32_bf16(ah[tm], bh[tn], acc[tm][tn], 0, 0, 0);
                acc[tm][tn] = __builtin_amdgcn_mfma_f32_16x16x32_bf16(al[tm], bh[tn], acc[tm][tn], 0, 0, 0);
                acc[tm][tn] = __builtin_amdgcn_mfma_f32_16x16x32_bf16(ah[tm], bl[tn], acc[tm][tn], 0, 0, 0);
            }
    }
}

// ---- qkv projection, 64M x 128N tiles (grid 12 x 64 = 768 = 3 blocks/CU,
// balanced; old 384-block grid left half the CUs with 2 resident blocks).
// Epilogue: round-3-verified structure (per-wn-slice shared 64x67 transpose
// buffer, both wm waves fill) with the round-8 V-permutation.
__global__ __launch_bounds__(256, 3) void gemm_qkv_mfma(const char* __restrict__ Aimg,
                                                        const char* __restrict__ Bimg,
                                                        const float* __restrict__ cosp,
                                                        const float* __restrict__ sinp,
                                                        float* __restrict__ Qf,
                                                        ushort* __restrict__ Kimg,
                                                        ushort* __restrict__ Vimg) {
    __shared__ __align__(16) char smem[49152];   // dbuf 48K; epilogue 2x17152
    const int tid = threadIdx.x;
    const int nt = blockIdx.x, mt = blockIdx.y;  // mt: 64-row tile (0..63)

    floatx4 acc[2][4];
    gemm_core64(Aimg, Bimg, smem, mt, nt, tid, acc);

    const int wv = tid >> 6;
    const int wm = wv & 1, wn = wv >> 1;
    const int lane = tid & 63;
    const int qd = lane >> 4, cl = lane & 15;

    const int slice = nt*2 + wn;          // 0..23
    const int g  = slice / 6;
    const int jj = slice % 6;
    const int b  = mt >> 5;

    // ---- RoPE in C-fragment space (Q and K): dims cl (tn=0) & 16+cl (tn=1)
    if (jj != 5) {
        #pragma unroll
        for (int tm = 0; tm < 2; ++tm)
            #pragma unroll
            for (int r = 0; r < 4; ++r) {
                int m = mt*64 + wm*32 + 16*tm + 4*qd + r;
                int t = m & 2047;
                float c1 = cosp[t*ROPEN + cl],      s1 = sinp[t*ROPEN + cl];
                float c2 = cosp[t*ROPEN + 16 + cl], s2 = sinp[t*ROPEN + 16 + cl];
                float x1 = acc[tm][0][r], x2 = acc[tm][1][r];
                acc[tm][0][r] = x1*c1 - x2*s1;
                acc[tm][1][r] = x2*c2 + x1*s2;
            }
    }

    if (jj < 4) {
        #pragma unroll
        for (int tm = 0; tm < 2; ++tm)
            #pragma unroll
            for (int tn = 0; tn < 4; ++tn)
                #pragma unroll
                for (int r = 0; r < 4; ++r) {
                    int m = mt*64 + wm*32 + 16*tm + 4*qd + r;
                    Qf[(size_t)m*1024 + (g*4 + jj)*64 + 16*tn + cl] = acc[tm][tn][r];
                }
    } else {
        // K/V: per-slice shared 64x67 transpose buffer (both wm waves fill).
        // Branch uniform per block: slices (2nt, 2nt+1) are both >=4 iff
        // nt in {2,5,8,11}.
        float* Lw = (float*)(smem + wn*17152);   // 64 x 67 f32 = 17152 B
        __syncthreads();   // main-loop LDS reads complete (uniform: KV block)
        #pragma unroll
        for (int tm = 0; tm < 2; ++tm)
            #pragma unroll
            for (int tn = 0; tn < 4; ++tn)
                #pragma unroll
                for (int r = 0; r < 4; ++r)
                    Lw[(wm*32 + 16*tm + 4*qd + r)*67 + 16*tn + cl] = acc[tm][tn][r];
        __syncthreads();

        const int cloc = mt & 31;                // 64-key tile index within b
        ushort* img = ((jj == 4) ? Kimg : Vimg)
                      + (size_t)(b*4 + g)*262144 + (size_t)cloc*8192;
        if (jj == 4) {
            // K: exact hi/lo split.  wave wm: rows [32wm,32wm+32); lane
            // halves split the 8 chunks.
            const int rr = wm*32 + (lane & 31);
            const int cb = (lane >> 5) * 4;
            float f[8];
            #pragma unroll
            for (int cc = 0; cc < 4; ++cc) {
                const int ch = cb + cc;
                *(float4*)f       = *(const float4*)(&Lw[rr*67 + ch*8]);
                *(float4*)(f + 4) = *(const float4*)(&Lw[rr*67 + ch*8 + 4]);
                uint4 h4, l4;
                split_pack8(f, h4, l4);
                int phys = ch ^ (rr & 7);
                *(uint4*)(img + rr*64 + phys*8)        = h4;
                *(uint4*)(img + 4096 + rr*64 + phys*8) = l4;
            }
        } else {
            // V: RTN hi only, permuted-key chunk layout (attn P order):
            // chunk ch holds keys {32(ch>>2)+4(ch&3)..+3} then {+16..+3}.
            const int d = lane;
            float f[8];
            #pragma unroll
            for (int cc = 0; cc < 4; ++cc) {
                const int ch = wm*4 + cc;
                const int kb = 32*(ch >> 2) + 4*(ch & 3);
                #pragma unroll
                for (int i = 0; i < 4; ++i) f[i]     = Lw[(kb + i)*67 + d];
                #pragma unroll
                for (int i = 0; i < 4; ++i) f[4 + i] = Lw[(kb + 16 + i)*67 + d];
                uint4 h4;
                rtn_pack8(f, h4);
                int phys = ch ^ (d & 7);
                *(uint4*)(img + d*64 + phys*8) = h4;   // hi only
            }
        }
    }
}

// ---- output projection: out = yb @ Wout, 64M x 128N tiles (round-13) ----
__global__ __launch_bounds__(256, 2) void gemm_out_mfma(const char* __restrict__ Aimg,
                                                        const char* __restrict__ Bimg,
                                                        float* __restrict__ C) {
    __shared__ __align__(16) char smem[49152];
    const int tid = threadIdx.x;
    const int nt = blockIdx.x, mt = blockIdx.y;   // mt: 64-row tile (0..63)

    floatx4 acc[2][4];
    gemm_core64(Aimg, Bimg, smem, mt, nt, tid, acc);

    const int wv = tid >> 6;
    const int wm = wv & 1, wn = wv >> 1;
    const int lane = tid & 63;
    const int qd = lane >> 4, cl = lane & 15;

    #pragma unroll
    for (int tm = 0; tm < 2; ++tm)
        #pragma unroll
        for (int tn = 0; tn < 4; ++tn)
            #pragma unroll
            for (int r = 0; r < 4; ++r) {
                int m = mt*64 + wm*32 + 16*tm + 4*qd + r;
                int n = nt*128 + wn*64 + 16*tn + cl;
                C[(size_t)m*1024 + n] = acc[tm][tn][r];
            }
}

// ---------------------------------------------------------------------------
// MFMA flash attention v15 (round-10 verified main loop).  Yimg epilogue
// remapped for linear stores: thread -> (row = tid>>2, slot-group = tid&3,
// region = cc); consecutive lanes write consecutive 16-B slots of one row
// (the slot XOR permutes within the row), rows sequential -> fully linear
// 8-KB streams per region-half.  (Round-13's j-fastest mapping interleaved
// two regions per thread and cost ~2.4 us in store coalescing.)
// ---------------------------------------------------------------------------
__global__ __launch_bounds__(512, 4) void attn15(const float* __restrict__ Qf,
                                                 const char* __restrict__ Kimg,
                                                 const char* __restrict__ Vimg,
                                                 char* __restrict__ Yimg) {
    __shared__ __align__(16) char smem[49152];   // K dbuf 32K | V dbuf 16K

    const int tid  = threadIdx.x;
    const int wv8  = tid >> 6;           // 0..7
    const int grp  = wv8 >> 2;           // key half within 64-key tile
    const int wq   = wv8 & 3;            // q quarter (32 rows)
    const int lane = tid & 63;
    const int qd   = lane >> 4;
    const int cl   = lane & 15;

    const int bg    = blockIdx.x & 7;    // XCD-aligned
    const int inner = blockIdx.x >> 3;   // 0..63
    const int hj    = inner >> 4;        // head within group (0..3)
    const int qt    = inner & 15;        // 128-row q tile (0..15)
    const int b = bg >> 2, g = bg & 3;
    const int h = g*4 + hj;

    // ---- Q fragments (rows wq*32 + rb*16 + cl) -> regs, scaled log2(e)/8 --
    short8 qh[2][2], ql[2][2];
    #pragma unroll
    for (int rb = 0; rb < 2; ++rb) {
        const float* qp = Qf + (size_t)(b*2048 + qt*128 + wq*32 + rb*16 + cl)*1024
                             + h*64 + 8*qd;
        #pragma unroll
        for (int s = 0; s < 2; ++s) {
            float f[8];
            *(float4*)f       = *(const float4*)(qp + 32*s);
            *(float4*)(f + 4) = *(const float4*)(qp + 32*s + 4);
            #pragma unroll
            for (int i = 0; i < 8; ++i) f[i] *= 0.125f * 1.44269504088896f;
            uint4 h4, l4;
            split_pack8(f, h4, l4);
            qh[rb][s] = __builtin_bit_cast(short8, h4);
            ql[rb][s] = __builtin_bit_cast(short8, l4);
        }
    }

    floatx4 accOT[2][4] = {};            // O^T partial: [rb][d-block], q = cl
    float lsum[2] = {};                  // softmax denom partials

    const char* Kg0 = Kimg + (size_t)bg*524288;
    const char* Vg0 = Vimg + (size_t)bg*524288;
    const int wslot = wv8 << 10;         // wave-uniform LDS byte offset (1K)

    // lane-constant V LDS offsets (chunk 4*grp+qd, phys ^(cl&7); 8K tile)
    int voff[4];
    #pragma unroll
    for (int tt = 0; tt < 4; ++tt)
        voff[tt] = (16*tt + cl)*128 + (((4*grp + qd) ^ (cl & 7))*16);

    // stage K 64-key tile 0 (hi 8K + lo 8K) + V tile 0 (8K), image-linear
    {
        const char* ksrc = Kg0 + (size_t)tid*16;
        lds_async16(smem + wslot,        ksrc);
        lds_async16(smem + 8192 + wslot, ksrc + 8192);
        lds_async16(smem + 32768 + wslot, Vg0 + (size_t)tid*16);
    }

    for (int c = 0; c < TSEQ/64; ++c) {
        __syncthreads();   // publishes K[c] + V[c]; all reads of c-1 complete
        const int buf = c & 1;

        if (c + 1 < TSEQ/64) {
            const char* ksrc = Kg0 + (size_t)(c+1)*16384 + (size_t)tid*16;
            const char* vsrc = Vg0 + (size_t)(c+1)*16384 + (size_t)tid*16;
            lds_async16(smem + (1-buf)*16384 + wslot,        ksrc);
            lds_async16(smem + (1-buf)*16384 + 8192 + wslot, ksrc + 8192);
            lds_async16(smem + 32768 + (1-buf)*8192 + wslot, vsrc);
        }
        const char* Kl = smem + buf*16384;
        const char* Vl = smem + 32768 + buf*8192;

        // ---- S^T = K.Q^T for this wave's 32-key half, BOTH row-blocks ----
        floatx4 accST[2][2] = {};
        __builtin_amdgcn_s_setprio(1);
        #pragma unroll
        for (int s = 0; s < 2; ++s) {
            #pragma unroll
            for (int tt = 0; tt < 2; ++tt) {
                const int off = (32*grp + 16*tt + cl)*128
                              + (((4*s + qd) ^ (cl & 7))*16);
                short8 kh = *(const short8*)(Kl + off);
                short8 kl = *(const short8*)(Kl + 8192 + off);
                #pragma unroll
                for (int rb = 0; rb < 2; ++rb) {
                    accST[rb][tt] = __builtin_amdgcn_mfma_f32_16x16x32_bf16(kh, qh[rb][s], accST[rb][tt], 0, 0, 0);
                    accST[rb][tt] = __builtin_amdgcn_mfma_f32_16x16x32_bf16(kh, ql[rb][s], accST[rb][tt], 0, 0, 0);
                    accST[rb][tt] = __builtin_amdgcn_mfma_f32_16x16x32_bf16(kl, qh[rb][s], accST[rb][tt], 0, 0, 0);
                }
            }
        }
        __builtin_amdgcn_s_setprio(0);

        // ---- softmax: exp2 (S in log2 units), pack in-register ----
        short8 pa[2];
        #pragma unroll
        for (int rb = 0; rb < 2; ++rb) {
            float p[8];
            #pragma unroll
            for (int tt = 0; tt < 2; ++tt)
                #pragma unroll
                for (int r = 0; r < 4; ++r)
                    p[4*tt + r] = fast_exp2(accST[rb][tt][r]);
            lsum[rb] += ((p[0] + p[1]) + (p[2] + p[3]))
                      + ((p[4] + p[5]) + (p[6] + p[7]));
            uint4 paw;
            paw.x = pk_bf16x2(p[0], p[1]);
            paw.y = pk_bf16x2(p[2], p[3]);
            paw.z = pk_bf16x2(p[4], p[5]);
            paw.w = pk_bf16x2(p[6], p[7]);
            pa[rb] = __builtin_bit_cast(short8, paw);
        }

        // ---- O^T += V.P (V from LDS, read once per tt, feeds both rb) ----
        __builtin_amdgcn_s_setprio(1);
        #pragma unroll
        for (int tt = 0; tt < 4; ++tt) {
            short8 vh = *(const short8*)(Vl + voff[tt]);
            #pragma unroll
            for (int rb = 0; rb < 2; ++rb)
                accOT[rb][tt] = __builtin_amdgcn_mfma_f32_16x16x32_bf16(vh, pa[rb], accOT[rb][tt], 0, 0, 0);
        }
        __builtin_amdgcn_s_setprio(0);
    }

    // ---- combine key-half groups, normalize, write y A-image (v2) ----
    __syncthreads();                 // all waves done with K/V buffers
    float* Pb = (float*)smem;        // grp=1 partials: 512 entries x 17 f32
    if (grp == 1) {
        #pragma unroll
        for (int rb = 0; rb < 2; ++rb) {
            float* dst = Pb + (size_t)(((wq*2 + rb)*64) + lane)*17;
            #pragma unroll
            for (int tt = 0; tt < 4; ++tt)
                #pragma unroll
                for (int r = 0; r < 4; ++r)
                    dst[4*tt + r] = accOT[rb][tt][r];
            dst[16] = lsum[rb];
        }
    }
    __syncthreads();
    float inv[2] = {1.f, 1.f};
    if (grp == 0) {
        #pragma unroll
        for (int rb = 0; rb < 2; ++rb) {
            const float* sp = Pb + (size_t)(((wq*2 + rb)*64) + lane)*17;
            #pragma unroll
            for (int tt = 0; tt < 4; ++tt)
                #pragma unroll
                for (int r = 0; r < 4; ++r)
                    accOT[rb][tt][r] += sp[4*tt + r];
            float l = lsum[rb] + sp[16];
            l += __shfl_xor(l, 16);
            l += __shfl_xor(l, 32);
            inv[rb] = 1.0f / l;
        }
    }
    __syncthreads();                 // Pb reads done -> region reusable as Lt
    float* Lt = (float*)smem;        // 128 rows x 66 f32 = 33792 B
    if (grp == 0) {
        #pragma unroll
        for (int rb = 0; rb < 2; ++rb) {
            const int row = wq*32 + rb*16 + cl;  // q row in 128-tile
            #pragma unroll
            for (int tt = 0; tt < 4; ++tt)
                #pragma unroll
                for (int r = 0; r < 4; ++r)
                    Lt[row*66 + 16*tt + 4*qd + r] = accOT[rb][tt][r] * inv[rb];
        }
    }
    __syncthreads();
    {
        // linear-store mapping: row = tid>>2, jsub = tid&3, region = cc.
        char* tbase = Yimg + ((size_t)(b*16 + qt)*32 + 2*h) * 16384;
        const int r0   = tid >> 2;    // 0..127 (q row)
        const int jsub = tid & 3;
        const int slot = jsub ^ ((r0 >> 1) & 3);
        #pragma unroll
        for (int cc = 0; cc < 2; ++cc) {
            const int j = cc*4 + jsub;   // 8-dim chunk
            float f[8];
            #pragma unroll
            for (int u = 0; u < 4; ++u)
                *(float2*)(f + 2*u) = *(const float2*)(&Lt[r0*66 + j*8 + 2*u]);
            uint4 h4, l4;
            split_pack8(f, h4, l4);
            char* reg = tbase + cc*16384;
            *(uint4*)(reg + r0*64 + slot*16)        = h4;
            *(uint4*)(reg + 8192 + r0*64 + slot*16) = l4;
        }
    }
}

// ---------------------------------------------------------------------------
extern "C" void kernel_launch(void* const* d_in, const int* in_sizes, int n_in,
                              void* d_out, int out_size, void* d_ws, size_t ws_size,
                              hipStream_t stream) {
    const float* x    = (const float*)d_in[0];
    const float* cosp = (const float*)d_in[1];
    const float* sinp = (const float*)d_in[2];
    // d_in[3] = mask: unused by the reference computation
    const float* Wqkv = (const float*)d_in[4];
    const float* Wout = (const float*)d_in[5];
    float* out = (float*)d_out;

    char* ws = (char*)d_ws;
    float*  Qf    = (float*)(ws);                      // [ 0,16M)
    ushort* Kimg  = (ushort*)(ws + ((size_t)16<<20));  // [16,20M)
    ushort* Vimg  = (ushort*)(ws + ((size_t)20<<20));  // [20,24M)
    char*   Bo    = ws + ((size_t)24<<20);             // [24,28M)
    char*   Ximg  = ws + ((size_t)28<<20);             // [28,44M)  (dead after qkv-gemm)
    char*   Bq    = ws + ((size_t)44<<20);             // [44,50M)
    char*   Yimg  = ws + ((size_t)28<<20);             // [28,44M)  (over dead Ximg)

    // 1) all input + weight images in ONE launch (832 blocks), format v2
    conv_all<<<832, 256, 0, stream>>>(x, Wqkv, Wout, Ximg, Bq, Bo);
    // 2) qkv projection + fused RoPE + K/V image build (768 blocks = 3/CU)
    gemm_qkv_mfma<<<dim3(12, 64), 256, 0, stream>>>(Ximg, Bq, cosp, sinp,
                                                    Qf, Kimg, Vimg);
    // 3) attention: 512 blocks x 512 thr, 128 q-rows/block
    attn15<<<512, 512, 0, stream>>>(Qf, (const char*)Kimg, (const char*)Vimg,
                                    Yimg);
    // 4) out = y @ Wout (v4 dbuf)
    gemm_out_mfma<<<dim3(8, 64), 256, 0, stream>>>(Yimg, Bo, out);
}

// Round 15
// 211.418 us; speedup vs baseline: 1.0326x; 1.0326x over previous
//
#include <hip/hip_runtime.h>
#include <hip/hip_bf16.h>
#include <math.h>

// Problem constants (fixed shapes)
#define BATCH   2
#define TSEQ    2048
#define DEMBED  1024
#define NHEAD   16
#define DHEAD   64
#define NGROUP  4
#define ROPEN   32
#define FQKV    1536          // (16 + 2*4) * 64
#define MROWS   (BATCH*TSEQ)  // 4096

typedef __attribute__((ext_vector_type(8))) short short8;   // 8 bf16 = 4 VGPR
typedef __attribute__((ext_vector_type(4))) float floatx4;  // MFMA C/D

// ---------------------------------------------------------------------------
// split helpers: f = hi + lo, hi = truncate-to-bf16(f), lo = bf16(f - hi).
// ---------------------------------------------------------------------------
__device__ __forceinline__ void split_pack8(const float* f, uint4& h4, uint4& l4) {
    uint u[8], lu[8];
    #pragma unroll
    for (int j = 0; j < 8; ++j) {
        u[j] = __float_as_uint(f[j]);
        float lf = f[j] - __uint_as_float(u[j] & 0xffff0000u);
        lu[j] = __float_as_uint(lf);
    }
    h4.x = __builtin_amdgcn_perm(u[1], u[0], 0x07060302u);
    h4.y = __builtin_amdgcn_perm(u[3], u[2], 0x07060302u);
    h4.z = __builtin_amdgcn_perm(u[5], u[4], 0x07060302u);
    h4.w = __builtin_amdgcn_perm(u[7], u[6], 0x07060302u);
    l4.x = __builtin_amdgcn_perm(lu[1], lu[0], 0x07060302u);
    l4.y = __builtin_amdgcn_perm(lu[3], lu[2], 0x07060302u);
    l4.z = __builtin_amdgcn_perm(lu[5], lu[4], 0x07060302u);
    l4.w = __builtin_amdgcn_perm(lu[7], lu[6], 0x07060302u);
}

// round-to-nearest bf16 pack of 8 floats -> hi-only uint4 (unbiased)
__device__ __forceinline__ void rtn_pack8(const float* f, uint4& h4) {
    uint t[8];
    #pragma unroll
    for (int j = 0; j < 8; ++j)
        t[j] = __float_as_uint(f[j]) + 0x8000u;
    h4.x = __builtin_amdgcn_perm(t[1], t[0], 0x07060302u);
    h4.y = __builtin_amdgcn_perm(t[3], t[2], 0x07060302u);
    h4.z = __builtin_amdgcn_perm(t[5], t[4], 0x07060302u);
    h4.w = __builtin_amdgcn_perm(t[7], t[6], 0x07060302u);
}

// pack two floats -> one u32 of two RTN bf16 (lo = f0, hi = f1)
__device__ __forceinline__ uint pk_bf16x2(float f0, float f1) {
    uint u0 = __float_as_uint(f0) + 0x8000u;
    uint u1 = __float_as_uint(f1) + 0x8000u;
    return __builtin_amdgcn_perm(u1, u0, 0x07060302u);
}

// native 2^x (single VOP1; log2 scaling folded into operands upstream)
__device__ __forceinline__ float fast_exp2(float x) {
    float r;
    asm("v_exp_f32 %0, %1" : "=v"(r) : "v"(x));
    return r;
}

// async 16B/lane global->LDS copy; lds must be wave-uniform (HW adds lane*16)
// INVARIANT (session-verified): LDS destination must stay < 64 KiB.
__device__ __forceinline__ void lds_async16(void* lds, const void* gp) {
    __builtin_amdgcn_global_load_lds(
        (const __attribute__((address_space(1))) unsigned int*)gp,
        (__attribute__((address_space(3))) unsigned int*)lds,
        16, 0, 0);
}

// ===========================================================================
// MFMA-GEMM images, format v2 (BK=32 native):
// per (tile128, kb32): contiguous 16 KB region = [hi: 128 rows x 64 B |
// lo: 128 rows x 64 B].  Region index = tile*32 + kb.  Row r holds the
// 32 k-values as 4 chunks of 16 B; logical chunk q stored at slot
// q ^ p(r), p(r) = (r>>1)&3.  Wave b128 read: conflict-free (8 lanes per
// 16-B bank group).  Enables linear 4-KB global_load_lds double-buffering
// below the 64-KiB async-dest envelope.
// ===========================================================================

// ---- x converter body: [4096][1024] f32 row-major -> A-image v2 ----
__device__ __forceinline__ void conv_xy_body(const float* __restrict__ in,
                                             char* __restrict__ img,
                                             int bid, int tid) {
    const int c   = bid & 15;        // 64-k block -> kb = 2c + half
    const int mt  = bid >> 4;
    const int r    = tid >> 1;
    const int half = tid & 1;

    const float* src = in + (size_t)(mt*128 + r)*1024 + c*64 + half*32;
    float f[32];
    #pragma unroll
    for (int u = 0; u < 8; ++u)
        *(float4*)(f + 4*u) = *(const float4*)(src + 4*u);

    char* reg = img + (size_t)(mt*32 + c*2 + half) * 16384;
    const int pr = (r >> 1) & 3;
    #pragma unroll
    for (int cc = 0; cc < 4; ++cc) {
        uint4 h4, l4;
        split_pack8(f + cc*8, h4, l4);
        int slot = cc ^ pr;
        *(uint4*)(reg + r*64 + slot*16)        = h4;
        *(uint4*)(reg + 8192 + r*64 + slot*16) = l4;
    }
}

// ---- weight converter body (transpose): W [1024][N] f32 -> B^T image v2 ----
__device__ __forceinline__ void conv_w_body(const float* __restrict__ W,
                                            int N, char* __restrict__ img,
                                            int c, int nt, int tid,
                                            float (*Lf)[132]) {
    {
        const int kk = tid >> 2;
        const int nc = (tid & 3) * 32;
        const float* src = W + (size_t)(c*64 + kk)*N + nt*128 + nc;
        #pragma unroll
        for (int u = 0; u < 8; ++u)
            *(float4*)(&Lf[kk][nc + 4*u]) = *(const float4*)(src + 4*u);
    }
    __syncthreads();

    char* tbase = img + (size_t)(nt*32 + c*2) * 16384;   // kb even; odd at +16K
    #pragma unroll
    for (int rep = 0; rep < 4; ++rep) {
        int idx = rep*256 + tid;
        int n = idx & 127;
        int j = idx >> 7;                 // logical 8-k chunk of the 64-k block
        float v[8];
        #pragma unroll
        for (int i = 0; i < 8; ++i) v[i] = Lf[j*8 + i][n];
        uint4 h4, l4;
        split_pack8(v, h4, l4);
        char* reg = tbase + (j >> 2)*16384;
        int slot = (j & 3) ^ ((n >> 1) & 3);
        *(uint4*)(reg + n*64 + slot*16)        = h4;
        *(uint4*)(reg + 8192 + n*64 + slot*16) = l4;
    }
}

// ---- merged converter: one launch covers x, Wqkv, Wout conversion ----
__global__ __launch_bounds__(256) void conv_all(const float* __restrict__ x,
                                                const float* __restrict__ Wqkv,
                                                const float* __restrict__ Wout,
                                                char* __restrict__ Ximg,
                                                char* __restrict__ Bq,
                                                char* __restrict__ Bo) {
    __shared__ float Lf[64][132];
    const int bid = blockIdx.x;
    const int tid = threadIdx.x;
    if (bid < 512) {
        conv_xy_body(x, Ximg, bid, tid);
    } else if (bid < 704) {
        const int idx = bid - 512;
        conv_w_body(Wqkv, FQKV, Bq, idx & 15, idx >> 4, tid, Lf);
    } else {
        const int idx = bid - 704;
        conv_w_body(Wout, DEMBED, Bo, idx & 15, idx >> 4, tid, Lf);
    }
}

// ---------------------------------------------------------------------------
// split-bf16 MFMA GEMM core v4 (round-13 verified): 128x128 tile, K-step 32,
// TRUE double buffer.  Per step: 8 linear 4-KB global_load_lds calls
// (A 16K + B 16K) into one of two 32-KB buffers; ONE barrier per step;
// prefetch of step c+1 issued after the barrier publishing step c.
// Buffer: [A-hi 8K][A-lo 8K][B-hi 8K][B-lo 8K]; dbuf max dest 65535.
// NOTE (rounds 3 & 14): 64-row qkv M-tiles regress — doubled per-block
// B staging outweighs the load-balance gain.  Keep 128-row tiles here.
// ---------------------------------------------------------------------------
struct GemmAcc { floatx4 a[4][4]; };

__device__ __forceinline__ void gemm_mfma_core(const char* __restrict__ Aimg,
                                               const char* __restrict__ Bimg,
                                               char* smem, int mt, int nt,
                                               int tid, GemmAcc& G) {
    const int wv = tid >> 6;
    const int wm = wv & 1, wn = wv >> 1;
    const int lane = tid & 63;
    const int qd = lane >> 4, cl = lane & 15;
    const int wslot = (tid & 192) * 16;     // wv*1024, wave-uniform
    const int slotx = (cl >> 1) & 3;

    #pragma unroll
    for (int tm = 0; tm < 4; ++tm)
        #pragma unroll
        for (int tn = 0; tn < 4; ++tn)
            G.a[tm][tn] = (floatx4){0.f, 0.f, 0.f, 0.f};

    // prologue: stage step 0 into buf 0
    {
        const char* srcA = Aimg + (size_t)(mt*32) * 16384 + (size_t)tid*16;
        const char* srcB = Bimg + (size_t)(nt*32) * 16384 + (size_t)tid*16;
        #pragma unroll
        for (int j = 0; j < 4; ++j) {
            lds_async16(smem + j*4096 + wslot,         srcA + j*4096);
            lds_async16(smem + 16384 + j*4096 + wslot, srcB + j*4096);
        }
    }

    for (int c = 0; c < 32; ++c) {
        __syncthreads();                    // publishes buf[c&1]; prev reads done
        const int buf = c & 1;
        if (c + 1 < 32) {
            const char* srcA = Aimg + (size_t)(mt*32 + c+1)*16384 + (size_t)tid*16;
            const char* srcB = Bimg + (size_t)(nt*32 + c+1)*16384 + (size_t)tid*16;
            char* dst = smem + (1 - buf)*32768;
            #pragma unroll
            for (int j = 0; j < 4; ++j) {
                lds_async16(dst + j*4096 + wslot,         srcA + j*4096);
                lds_async16(dst + 16384 + j*4096 + wslot, srcB + j*4096);
            }
        }
        const char* S = smem + buf*32768;

        short8 ah[4], al[4], bh[4], bl[4];
        #pragma unroll
        for (int tt = 0; tt < 4; ++tt) {
            const int ra = (wm*64 + 16*tt + cl)*64 + ((qd ^ slotx)*16);
            ah[tt] = *(const short8*)(S + ra);
            al[tt] = *(const short8*)(S + 8192 + ra);
            const int rb = (wn*64 + 16*tt + cl)*64 + ((qd ^ slotx)*16);
            bh[tt] = *(const short8*)(S + 16384 + rb);
            bl[tt] = *(const short8*)(S + 24576 + rb);
        }
        #pragma unroll
        for (int tm = 0; tm < 4; ++tm)
            #pragma unroll
            for (int tn = 0; tn < 4; ++tn) {
                G.a[tm][tn] = __builtin_amdgcn_mfma_f32_16x16x32_bf16(ah[tm], bh[tn], G.a[tm][tn], 0, 0, 0);
                G.a[tm][tn] = __builtin_amdgcn_mfma_f32_16x16x32_bf16(al[tm], bh[tn], G.a[tm][tn], 0, 0, 0);
                G.a[tm][tn] = __builtin_amdgcn_mfma_f32_16x16x32_bf16(ah[tm], bl[tn], G.a[tm][tn], 0, 0, 0);
            }
    }
}

// ---- qkv projection with fused RoPE + K/V image epilogue (round-13) ----
// V image chunk contents are permuted to match attn's in-register P layout:
// chunk j (=4*hh+qd) of a 64-key tile holds keys {32hh+4qd..+3} then
// {32hh+16+4qd..+3}.  attn-side addresses unchanged.
__global__ __launch_bounds__(256, 2) void gemm_qkv_mfma(const char* __restrict__ Aimg,
                                                        const char* __restrict__ Bimg,
                                                        const float* __restrict__ cosp,
                                                        const float* __restrict__ sinp,
                                                        float* __restrict__ Qf,
                                                        ushort* __restrict__ Kimg,
                                                        ushort* __restrict__ Vimg) {
    __shared__ __align__(16) char smem[68608];   // main loop uses [0,65536)
    const int tid = threadIdx.x;
    const int nt = blockIdx.x, mt = blockIdx.y;

    GemmAcc G;
    gemm_mfma_core(Aimg, Bimg, smem, mt, nt, tid, G);

    const int wv = tid >> 6;
    const int wm = wv & 1, wn = wv >> 1;
    const int lane = tid & 63;
    const int qd = lane >> 4, cl = lane & 15;

    const int slice = nt*2 + wn;          // 0..23
    const int g  = slice / 6;
    const int jj = slice % 6;
    const int b  = mt >> 4;

    // ---- RoPE in C-fragment space (Q and K): dims cl (tn=0) & 16+cl (tn=1)
    if (jj != 5) {
        #pragma unroll
        for (int tm = 0; tm < 4; ++tm)
            #pragma unroll
            for (int r = 0; r < 4; ++r) {
                int m = mt*128 + wm*64 + 16*tm + 4*qd + r;
                int t = m & 2047;
                float c1 = cosp[t*ROPEN + cl],      s1 = sinp[t*ROPEN + cl];
                float c2 = cosp[t*ROPEN + 16 + cl], s2 = sinp[t*ROPEN + 16 + cl];
                float x1 = G.a[tm][0][r], x2 = G.a[tm][1][r];
                G.a[tm][0][r] = x1*c1 - x2*s1;
                G.a[tm][1][r] = x2*c2 + x1*s2;
            }
    }

    if (jj < 4) {
        #pragma unroll
        for (int tm = 0; tm < 4; ++tm)
            #pragma unroll
            for (int tn = 0; tn < 4; ++tn)
                #pragma unroll
                for (int r = 0; r < 4; ++r) {
                    int m = mt*128 + wm*64 + 16*tm + 4*qd + r;
                    Qf[(size_t)m*1024 + (g*4 + jj)*64 + 16*tn + cl] = G.a[tm][tn][r];
                }
    } else {
        // K/V: wave-private LDS transpose -> swizzled image
        // K: exact hi/lo split (truncate).  V: RTN hi only (attn uses hi only).
        float* Lw = (float*)(smem + wv*17152);   // 64 x 67 f32
        __syncthreads();   // main-loop LDS reads complete (uniform: KV block)
        #pragma unroll
        for (int tm = 0; tm < 4; ++tm)
            #pragma unroll
            for (int tn = 0; tn < 4; ++tn)
                #pragma unroll
                for (int r = 0; r < 4; ++r)
                    Lw[(16*tm + 4*qd + r)*67 + 16*tn + cl] = G.a[tm][tn][r];
        __syncthreads();

        const int cloc = (mt & 15)*2 + wm;       // 64-key tile index within b
        ushort* img = ((jj == 4) ? Kimg : Vimg)
                      + (size_t)(b*4 + g)*262144 + (size_t)cloc*8192;
        if (jj == 4) {
            const int rr = lane;
            float f[8];
            #pragma unroll
            for (int ch = 0; ch < 8; ++ch) {
                *(float4*)f       = *(const float4*)(&Lw[rr*67 + ch*8]);
                *(float4*)(f + 4) = *(const float4*)(&Lw[rr*67 + ch*8 + 4]);
                uint4 h4, l4;
                split_pack8(f, h4, l4);
                int phys = ch ^ (rr & 7);
                *(uint4*)(img + rr*64 + phys*8)        = h4;
                *(uint4*)(img + 4096 + rr*64 + phys*8) = l4;
            }
        } else {
            // V: permuted-key chunk layout (attn P-register order)
            const int d = lane;
            float f[8];
            #pragma unroll
            for (int ch = 0; ch < 8; ++ch) {
                const int kb = 32*(ch >> 2) + 4*(ch & 3);
                #pragma unroll
                for (int i = 0; i < 4; ++i) f[i]     = Lw[(kb + i)*67 + d];
                #pragma unroll
                for (int i = 0; i < 4; ++i) f[4 + i] = Lw[(kb + 16 + i)*67 + d];
                uint4 h4;
                rtn_pack8(f, h4);
                int phys = ch ^ (d & 7);
                *(uint4*)(img + d*64 + phys*8) = h4;   // hi only
            }
        }
    }
}

// ---------------------------------------------------------------------------
// GEMM core "64": 64M x 128N tile, K-step 32, TRUE double buffer (round-13
// verified; used by gemm_out).  Buffer: [A-hi 4K][A-lo 4K][B-hi 8K][B-lo 8K]
// = 24 KB; dbuf 48 KB, dests < 64 KiB.
// ---------------------------------------------------------------------------
__device__ __forceinline__ void gemm_core64(const char* __restrict__ Aimg,
                                            const char* __restrict__ Bimg,
                                            char* smem, int amt, int nt,
                                            int tid, floatx4 (*acc)[4]) {
    const int wv = tid >> 6;
    const int wm = wv & 1, wn = wv >> 1;
    const int lane = tid & 63;
    const int qd = lane >> 4, cl = lane & 15;
    const int wslot = (tid & 192) * 16;
    const int slotx = (cl >> 1) & 3;
    const int ahalf = (amt & 1) * 4096;

    #pragma unroll
    for (int tm = 0; tm < 2; ++tm)
        #pragma unroll
        for (int tn = 0; tn < 4; ++tn)
            acc[tm][tn] = (floatx4){0.f, 0.f, 0.f, 0.f};

    // prologue: stage step 0 into buf 0
    {
        const char* gA = Aimg + (size_t)((amt >> 1)*32)*16384 + (size_t)tid*16;
        const char* gB = Bimg + (size_t)(nt*32)*16384 + (size_t)tid*16;
        lds_async16(smem + wslot,        gA + ahalf);
        lds_async16(smem + 4096 + wslot, gA + 8192 + ahalf);
        #pragma unroll
        for (int j = 0; j < 4; ++j)
            lds_async16(smem + 8192 + j*4096 + wslot, gB + j*4096);
    }

    for (int c = 0; c < 32; ++c) {
        __syncthreads();                    // publishes buf[c&1]; prev reads done
        const int buf = c & 1;
        if (c + 1 < 32) {
            const char* gA = Aimg + (size_t)((amt >> 1)*32 + c+1)*16384 + (size_t)tid*16;
            const char* gB = Bimg + (size_t)(nt*32 + c+1)*16384 + (size_t)tid*16;
            char* dst = smem + (1 - buf)*24576;
            lds_async16(dst + wslot,        gA + ahalf);
            lds_async16(dst + 4096 + wslot, gA + 8192 + ahalf);
            #pragma unroll
            for (int j = 0; j < 4; ++j)
                lds_async16(dst + 8192 + j*4096 + wslot, gB + j*4096);
        }
        const char* S = smem + buf*24576;

        short8 ah[2], al[2], bh[4], bl[4];
        #pragma unroll
        for (int tt = 0; tt < 2; ++tt) {
            const int ra = (wm*32 + 16*tt + cl)*64 + ((qd ^ slotx)*16);
            ah[tt] = *(const short8*)(S + ra);
            al[tt] = *(const short8*)(S + 4096 + ra);
        }
        #pragma unroll
        for (int tt = 0; tt < 4; ++tt) {
            const int rb = (wn*64 + 16*tt + cl)*64 + ((qd ^ slotx)*16);
            bh[tt] = *(const short8*)(S + 8192 + rb);
            bl[tt] = *(const short8*)(S + 16384 + rb);
        }
        #pragma unroll
        for (int tm = 0; tm < 2; ++tm)
            #pragma unroll
            for (int tn = 0; tn < 4; ++tn) {
                acc[tm][tn] = __builtin_amdgcn_mfma_f32_16x16x32_bf16(ah[tm], bh[tn], acc[tm][tn], 0, 0, 0);
                acc[tm][tn] = __builtin_amdgcn_mfma_f32_16x16x32_bf16(al[tm], bh[tn], acc[tm][tn], 0, 0, 0);
                acc[tm][tn] = __builtin_amdgcn_mfma_f32_16x16x32_bf16(ah[tm], bl[tn], acc[tm][tn], 0, 0, 0);
            }
    }
}

// ---- output projection: out = yb @ Wout, 64M x 128N tiles (round-13) ----
__global__ __launch_bounds__(256, 2) void gemm_out_mfma(const char* __restrict__ Aimg,
                                                        const char* __restrict__ Bimg,
                                                        float* __restrict__ C) {
    __shared__ __align__(16) char smem[49152];
    const int tid = threadIdx.x;
    const int nt = blockIdx.x, mt = blockIdx.y;   // mt: 64-row tile (0..63)

    floatx4 acc[2][4];
    gemm_core64(Aimg, Bimg, smem, mt, nt, tid, acc);

    const int wv = tid >> 6;
    const int wm = wv & 1, wn = wv >> 1;
    const int lane = tid & 63;
    const int qd = lane >> 4, cl = lane & 15;

    #pragma unroll
    for (int tm = 0; tm < 2; ++tm)
        #pragma unroll
        for (int tn = 0; tn < 4; ++tn)
            #pragma unroll
            for (int r = 0; r < 4; ++r) {
                int m = mt*64 + wm*32 + 16*tm + 4*qd + r;
                int n = nt*128 + wn*64 + 16*tn + cl;
                C[(size_t)m*1024 + n] = acc[tm][tn][r];
            }
}

// ---------------------------------------------------------------------------
// MFMA flash attention v15 (round-14 verified: 66.2 us, MfmaUtil 44,
// SQ_LDS_BANK_CONFLICT = 0).  512-thr blocks, 8 waves (grp x wq); 128
// q-rows/block; K/V staged via dbuf global_load_lds; register-resident P
// (permuted V image); grp partials combined via LDS; linear-store Yimg
// epilogue (row = tid>>2, slot-group = tid&3, region = cc).
// ---------------------------------------------------------------------------
__global__ __launch_bounds__(512, 4) void attn15(const float* __restrict__ Qf,
                                                 const char* __restrict__ Kimg,
                                                 const char* __restrict__ Vimg,
                                                 char* __restrict__ Yimg) {
    __shared__ __align__(16) char smem[49152];   // K dbuf 32K | V dbuf 16K

    const int tid  = threadIdx.x;
    const int wv8  = tid >> 6;           // 0..7
    const int grp  = wv8 >> 2;           // key half within 64-key tile
    const int wq   = wv8 & 3;            // q quarter (32 rows)
    const int lane = tid & 63;
    const int qd   = lane >> 4;
    const int cl   = lane & 15;

    const int bg    = blockIdx.x & 7;    // XCD-aligned
    const int inner = blockIdx.x >> 3;   // 0..63
    const int hj    = inner >> 4;        // head within group (0..3)
    const int qt    = inner & 15;        // 128-row q tile (0..15)
    const int b = bg >> 2, g = bg & 3;
    const int h = g*4 + hj;

    // ---- Q fragments (rows wq*32 + rb*16 + cl) -> regs, scaled log2(e)/8 --
    short8 qh[2][2], ql[2][2];
    #pragma unroll
    for (int rb = 0; rb < 2; ++rb) {
        const float* qp = Qf + (size_t)(b*2048 + qt*128 + wq*32 + rb*16 + cl)*1024
                             + h*64 + 8*qd;
        #pragma unroll
        for (int s = 0; s < 2; ++s) {
            float f[8];
            *(float4*)f       = *(const float4*)(qp + 32*s);
            *(float4*)(f + 4) = *(const float4*)(qp + 32*s + 4);
            #pragma unroll
            for (int i = 0; i < 8; ++i) f[i] *= 0.125f * 1.44269504088896f;
            uint4 h4, l4;
            split_pack8(f, h4, l4);
            qh[rb][s] = __builtin_bit_cast(short8, h4);
            ql[rb][s] = __builtin_bit_cast(short8, l4);
        }
    }

    floatx4 accOT[2][4] = {};            // O^T partial: [rb][d-block], q = cl
    float lsum[2] = {};                  // softmax denom partials

    const char* Kg0 = Kimg + (size_t)bg*524288;
    const char* Vg0 = Vimg + (size_t)bg*524288;
    const int wslot = wv8 << 10;         // wave-uniform LDS byte offset (1K)

    // lane-constant V LDS offsets (chunk 4*grp+qd, phys ^(cl&7); 8K tile)
    int voff[4];
    #pragma unroll
    for (int tt = 0; tt < 4; ++tt)
        voff[tt] = (16*tt + cl)*128 + (((4*grp + qd) ^ (cl & 7))*16);

    // stage K 64-key tile 0 (hi 8K + lo 8K) + V tile 0 (8K), image-linear
    {
        const char* ksrc = Kg0 + (size_t)tid*16;
        lds_async16(smem + wslot,        ksrc);
        lds_async16(smem + 8192 + wslot, ksrc + 8192);
        lds_async16(smem + 32768 + wslot, Vg0 + (size_t)tid*16);
    }

    for (int c = 0; c < TSEQ/64; ++c) {
        __syncthreads();   // publishes K[c] + V[c]; all reads of c-1 complete
        const int buf = c & 1;

        if (c + 1 < TSEQ/64) {
            const char* ksrc = Kg0 + (size_t)(c+1)*16384 + (size_t)tid*16;
            const char* vsrc = Vg0 + (size_t)(c+1)*16384 + (size_t)tid*16;
            lds_async16(smem + (1-buf)*16384 + wslot,        ksrc);
            lds_async16(smem + (1-buf)*16384 + 8192 + wslot, ksrc + 8192);
            lds_async16(smem + 32768 + (1-buf)*8192 + wslot, vsrc);
        }
        const char* Kl = smem + buf*16384;
        const char* Vl = smem + 32768 + buf*8192;

        // ---- S^T = K.Q^T for this wave's 32-key half, BOTH row-blocks ----
        floatx4 accST[2][2] = {};
        __builtin_amdgcn_s_setprio(1);
        #pragma unroll
        for (int s = 0; s < 2; ++s) {
            #pragma unroll
            for (int tt = 0; tt < 2; ++tt) {
                const int off = (32*grp + 16*tt + cl)*128
                              + (((4*s + qd) ^ (cl & 7))*16);
                short8 kh = *(const short8*)(Kl + off);
                short8 kl = *(const short8*)(Kl + 8192 + off);
                #pragma unroll
                for (int rb = 0; rb < 2; ++rb) {
                    accST[rb][tt] = __builtin_amdgcn_mfma_f32_16x16x32_bf16(kh, qh[rb][s], accST[rb][tt], 0, 0, 0);
                    accST[rb][tt] = __builtin_amdgcn_mfma_f32_16x16x32_bf16(kh, ql[rb][s], accST[rb][tt], 0, 0, 0);
                    accST[rb][tt] = __builtin_amdgcn_mfma_f32_16x16x32_bf16(kl, qh[rb][s], accST[rb][tt], 0, 0, 0);
                }
            }
        }
        __builtin_amdgcn_s_setprio(0);

        // ---- softmax: exp2 (S in log2 units), pack in-register ----
        short8 pa[2];
        #pragma unroll
        for (int rb = 0; rb < 2; ++rb) {
            float p[8];
            #pragma unroll
            for (int tt = 0; tt < 2; ++tt)
                #pragma unroll
                for (int r = 0; r < 4; ++r)
                    p[4*tt + r] = fast_exp2(accST[rb][tt][r]);
            lsum[rb] += ((p[0] + p[1]) + (p[2] + p[3]))
                      + ((p[4] + p[5]) + (p[6] + p[7]));
            uint4 paw;
            paw.x = pk_bf16x2(p[0], p[1]);
            paw.y = pk_bf16x2(p[2], p[3]);
            paw.z = pk_bf16x2(p[4], p[5]);
            paw.w = pk_bf16x2(p[6], p[7]);
            pa[rb] = __builtin_bit_cast(short8, paw);
        }

        // ---- O^T += V.P (V from LDS, read once per tt, feeds both rb) ----
        __builtin_amdgcn_s_setprio(1);
        #pragma unroll
        for (int tt = 0; tt < 4; ++tt) {
            short8 vh = *(const short8*)(Vl + voff[tt]);
            #pragma unroll
            for (int rb = 0; rb < 2; ++rb)
                accOT[rb][tt] = __builtin_amdgcn_mfma_f32_16x16x32_bf16(vh, pa[rb], accOT[rb][tt], 0, 0, 0);
        }
        __builtin_amdgcn_s_setprio(0);
    }

    // ---- combine key-half groups, normalize, write y A-image (v2) ----
    __syncthreads();                 // all waves done with K/V buffers
    float* Pb = (float*)smem;        // grp=1 partials: 512 entries x 17 f32
    if (grp == 1) {
        #pragma unroll
        for (int rb = 0; rb < 2; ++rb) {
            float* dst = Pb + (size_t)(((wq*2 + rb)*64) + lane)*17;
            #pragma unroll
            for (int tt = 0; tt < 4; ++tt)
                #pragma unroll
                for (int r = 0; r < 4; ++r)
                    dst[4*tt + r] = accOT[rb][tt][r];
            dst[16] = lsum[rb];
        }
    }
    __syncthreads();
    float inv[2] = {1.f, 1.f};
    if (grp == 0) {
        #pragma unroll
        for (int rb = 0; rb < 2; ++rb) {
            const float* sp = Pb + (size_t)(((wq*2 + rb)*64) + lane)*17;
            #pragma unroll
            for (int tt = 0; tt < 4; ++tt)
                #pragma unroll
                for (int r = 0; r < 4; ++r)
                    accOT[rb][tt][r] += sp[4*tt + r];
            float l = lsum[rb] + sp[16];
            l += __shfl_xor(l, 16);
            l += __shfl_xor(l, 32);
            inv[rb] = 1.0f / l;
        }
    }
    __syncthreads();                 // Pb reads done -> region reusable as Lt
    float* Lt = (float*)smem;        // 128 rows x 66 f32 = 33792 B
    if (grp == 0) {
        #pragma unroll
        for (int rb = 0; rb < 2; ++rb) {
            const int row = wq*32 + rb*16 + cl;  // q row in 128-tile
            #pragma unroll
            for (int tt = 0; tt < 4; ++tt)
                #pragma unroll
                for (int r = 0; r < 4; ++r)
                    Lt[row*66 + 16*tt + 4*qd + r] = accOT[rb][tt][r] * inv[rb];
        }
    }
    __syncthreads();
    {
        // linear-store mapping: row = tid>>2, jsub = tid&3, region = cc.
        char* tbase = Yimg + ((size_t)(b*16 + qt)*32 + 2*h) * 16384;
        const int r0   = tid >> 2;    // 0..127 (q row)
        const int jsub = tid & 3;
        const int slot = jsub ^ ((r0 >> 1) & 3);
        #pragma unroll
        for (int cc = 0; cc < 2; ++cc) {
            const int j = cc*4 + jsub;   // 8-dim chunk
            float f[8];
            #pragma unroll
            for (int u = 0; u < 4; ++u)
                *(float2*)(f + 2*u) = *(const float2*)(&Lt[r0*66 + j*8 + 2*u]);
            uint4 h4, l4;
            split_pack8(f, h4, l4);
            char* reg = tbase + cc*16384;
            *(uint4*)(reg + r0*64 + slot*16)        = h4;
            *(uint4*)(reg + 8192 + r0*64 + slot*16) = l4;
        }
    }
}

// ---------------------------------------------------------------------------
extern "C" void kernel_launch(void* const* d_in, const int* in_sizes, int n_in,
                              void* d_out, int out_size, void* d_ws, size_t ws_size,
                              hipStream_t stream) {
    const float* x    = (const float*)d_in[0];
    const float* cosp = (const float*)d_in[1];
    const float* sinp = (const float*)d_in[2];
    // d_in[3] = mask: unused by the reference computation
    const float* Wqkv = (const float*)d_in[4];
    const float* Wout = (const float*)d_in[5];
    float* out = (float*)d_out;

    char* ws = (char*)d_ws;
    float*  Qf    = (float*)(ws);                      // [ 0,16M)
    ushort* Kimg  = (ushort*)(ws + ((size_t)16<<20));  // [16,20M)
    ushort* Vimg  = (ushort*)(ws + ((size_t)20<<20));  // [20,24M)
    char*   Bo    = ws + ((size_t)24<<20);             // [24,28M)
    char*   Ximg  = ws + ((size_t)28<<20);             // [28,44M)  (dead after qkv-gemm)
    char*   Bq    = ws + ((size_t)44<<20);             // [44,50M)
    char*   Yimg  = ws + ((size_t)28<<20);             // [28,44M)  (over dead Ximg)

    // 1) all input + weight images in ONE launch (832 blocks), format v2
    conv_all<<<832, 256, 0, stream>>>(x, Wqkv, Wout, Ximg, Bq, Bo);
    // 2) qkv projection + fused RoPE + K/V image build (round-13 config:
    //    128x128 v4-dbuf core, grid 12 x 32)
    gemm_qkv_mfma<<<dim3(12, 32), 256, 0, stream>>>(Ximg, Bq, cosp, sinp,
                                                    Qf, Kimg, Vimg);
    // 3) attention: 512 blocks x 512 thr, 128 q-rows/block (linear-store epi)
    attn15<<<512, 512, 0, stream>>>(Qf, (const char*)Kimg, (const char*)Vimg,
                                    Yimg);
    // 4) out = y @ Wout (core64 dbuf)
    gemm_out_mfma<<<dim3(8, 64), 256, 0, stream>>>(Yimg, Bo, out);
}